// Round 2
// baseline (2910.869 us; speedup 1.0000x reference)
//
#include <hip/hip_runtime.h>
#include <hip/hip_bf16.h>
#include <math.h>

#define B_  1024
#define S_  64
#define I_  2048
#define H_  2048
#define HI_ 2048
#define L_  4
#define NH_ 16
#define HD_ 128
#define H2_ 4096

typedef __attribute__((ext_vector_type(4))) float floatx4;
typedef __attribute__((ext_vector_type(8))) short shortx8;

__device__ __forceinline__ unsigned short f2bf(float f) {
  union { float f; unsigned int u; } v; v.f = f;
  unsigned int u = v.u;
  return (unsigned short)((u + 0x7fffu + ((u >> 16) & 1u)) >> 16);
}

enum { EPI_TS = 0, EPI_BIAS = 1, EPI_RES = 2, EPI_SIG = 3, EPI_GRU = 4 };

// Generic 64x64-tile bf16-MFMA GEMM: C = epi(A @ B + bias)
// A: [M,K] f32 (lda=K), or CONCAT: [Ax | Ah(*Ar)] each [M,H_] pitch H_.
// B: [K,N] f32 row-major. LDS: lds_a[m][k], lds_b[n][k], pitch 40 (2-way max).
template<int EPI, bool CONCAT, bool MULR, bool GATE3>
__global__ __launch_bounds__(256) void gemm_std(
    int M, int N, int K,
    const float* __restrict__ A,
    const float* __restrict__ Ax, const float* __restrict__ Ah, const float* __restrict__ Ar,
    const float* __restrict__ B0, const float* __restrict__ B1, const float* __restrict__ B2,
    const float* __restrict__ bias0, const float* __restrict__ bias1, const float* __restrict__ bias2,
    const float* __restrict__ tse, const int* __restrict__ tsp,
    const float* __restrict__ res,
    const float* __restrict__ Up, const float* __restrict__ Sp, const float* __restrict__ Hp,
    float* __restrict__ C0, float* __restrict__ C1, float* __restrict__ C2)
{
  const int t = threadIdx.x;
  const int wid = t >> 6, lane = t & 63, lr = lane & 15, lg = lane >> 4;
  const int wr = wid >> 1, wc = wid & 1;
  const int m_base = blockIdx.x * 64, n_base = blockIdx.y * 64;

  const float* Bm = B0; const float* bias = bias0; float* Cout = C0;
  if (GATE3) {
    int z = blockIdx.z;
    if (z == 1) { Bm = B1; bias = bias1; Cout = C1; }
    else if (z == 2) { Bm = B2; bias = bias2; Cout = C2; }
  }

  __shared__ unsigned short lds_a[64 * 40];
  __shared__ unsigned short lds_b[64 * 40];

  floatx4 acc[2][2] = {};
  const int nkt = K >> 5;
  for (int kt = 0; kt < nkt; ++kt) {
    // ---- stage A tile [64 m][32 k] -> lds_a[m][k]
    #pragma unroll
    for (int rep = 0; rep < 2; ++rep) {
      int idx = t + rep * 256;
      int arow = idx >> 3, c4 = idx & 7;
      int gk = (kt << 5) + c4 * 4;
      int grow = m_base + arow;
      float4 av;
      if (!CONCAT) {
        av = *(const float4*)(A + (size_t)grow * K + gk);
      } else {
        if (gk < H_) {
          av = *(const float4*)(Ax + (size_t)grow * H_ + gk);
        } else {
          av = *(const float4*)(Ah + (size_t)grow * H_ + (gk - H_));
          if (MULR) {
            float4 rv = *(const float4*)(Ar + (size_t)grow * H_ + (gk - H_));
            av.x *= rv.x; av.y *= rv.y; av.z *= rv.z; av.w *= rv.w;
          }
        }
      }
      ushort4 uv; uv.x = f2bf(av.x); uv.y = f2bf(av.y); uv.z = f2bf(av.z); uv.w = f2bf(av.w);
      *(ushort4*)&lds_a[arow * 40 + c4 * 4] = uv;
    }
    // ---- stage B tile [32 k][64 n] -> lds_b[n][k] (paired-k pack for b32 writes)
    {
      int tcol = t & 15, trow = t >> 4;           // trow: k-pair 0..15
      int gk = (kt << 5) + trow * 2;
      int gn = n_base + tcol * 4;
      float4 b0v = *(const float4*)(Bm + (size_t)gk * N + gn);
      float4 b1v = *(const float4*)(Bm + (size_t)(gk + 1) * N + gn);
      const float* p0 = &b0v.x; const float* p1 = &b1v.x;
      #pragma unroll
      for (int j = 0; j < 4; ++j) {
        ushort2 pr; pr.x = f2bf(p0[j]); pr.y = f2bf(p1[j]);
        *(ushort2*)&lds_b[(tcol * 4 + j) * 40 + trow * 2] = pr;
      }
    }
    __syncthreads();
    shortx8 af[2], bfv[2];
    #pragma unroll
    for (int mt = 0; mt < 2; ++mt)
      af[mt] = *(shortx8*)&lds_a[(wr * 32 + mt * 16 + lr) * 40 + lg * 8];
    #pragma unroll
    for (int nt = 0; nt < 2; ++nt)
      bfv[nt] = *(shortx8*)&lds_b[(wc * 32 + nt * 16 + lr) * 40 + lg * 8];
    #pragma unroll
    for (int mt = 0; mt < 2; ++mt)
      #pragma unroll
      for (int nt = 0; nt < 2; ++nt)
        acc[mt][nt] = __builtin_amdgcn_mfma_f32_16x16x32_bf16(af[mt], bfv[nt], acc[mt][nt], 0, 0, 0);
    __syncthreads();
  }

  int ts = 0;
  if (EPI == EPI_TS) ts = tsp[0];
  #pragma unroll
  for (int mt = 0; mt < 2; ++mt)
  #pragma unroll
  for (int nt = 0; nt < 2; ++nt)
  #pragma unroll
  for (int j = 0; j < 4; ++j) {
    int row = m_base + wr * 32 + mt * 16 + lg * 4 + j;
    int col = n_base + wc * 32 + nt * 16 + lr;
    size_t idx = (size_t)row * N + col;
    float v = acc[mt][nt][j];
    if (EPI == EPI_TS)        v += bias[col] + tse[(size_t)ts * H_ + col];
    else if (EPI == EPI_BIAS) v += bias[col];
    else if (EPI == EPI_RES)  v += bias[col] + res[idx];
    else if (EPI == EPI_SIG)  { v += bias[col]; v = 1.f / (1.f + expf(-v)); }
    else if (EPI == EPI_GRU) {
      v += bias[col];
      float gl = 0.5f * v * (1.f + erff(v * 0.70710678118654752f));
      float u = Up[idx], s = Sp[idx], h = Hp[idx];
      v = (1.f - u) * h + u * (s * gl + (1.f - s) * h);
    }
    Cout[idx] = v;
  }
}

// T[b,h,i] = sum_d q[b, h*HD+d] * Wk[i, h*HD+d]   (per-head q-through-Wk^T)
__global__ __launch_bounds__(256) void gemm_t(
    const float* __restrict__ Q, const float* __restrict__ Wk, unsigned short* __restrict__ T)
{
  const int t = threadIdx.x;
  const int wid = t >> 6, lane = t & 63, lr = lane & 15, lg = lane >> 4;
  const int wr = wid >> 1, wc = wid & 1;
  const int h = blockIdx.z;
  const int m_base = blockIdx.x * 64, n_base = blockIdx.y * 64;
  __shared__ unsigned short lds_a[64 * 40];
  __shared__ unsigned short lds_b[64 * 40];
  floatx4 acc[2][2] = {};
  for (int kt = 0; kt < 4; ++kt) {
    #pragma unroll
    for (int rep = 0; rep < 2; ++rep) {
      int idx = t + rep * 256;
      int arow = idx >> 3, c4 = idx & 7;
      int gk = kt * 32 + c4 * 4;
      float4 av = *(const float4*)(Q + (size_t)(m_base + arow) * H_ + h * HD_ + gk);
      ushort4 ua; ua.x = f2bf(av.x); ua.y = f2bf(av.y); ua.z = f2bf(av.z); ua.w = f2bf(av.w);
      *(ushort4*)&lds_a[arow * 40 + c4 * 4] = ua;
      float4 bv = *(const float4*)(Wk + (size_t)(n_base + arow) * H_ + h * HD_ + gk);
      ushort4 ub; ub.x = f2bf(bv.x); ub.y = f2bf(bv.y); ub.z = f2bf(bv.z); ub.w = f2bf(bv.w);
      *(ushort4*)&lds_b[arow * 40 + c4 * 4] = ub;
    }
    __syncthreads();
    shortx8 af[2], bfv[2];
    #pragma unroll
    for (int mt = 0; mt < 2; ++mt)
      af[mt] = *(shortx8*)&lds_a[(wr * 32 + mt * 16 + lr) * 40 + lg * 8];
    #pragma unroll
    for (int nt = 0; nt < 2; ++nt)
      bfv[nt] = *(shortx8*)&lds_b[(wc * 32 + nt * 16 + lr) * 40 + lg * 8];
    #pragma unroll
    for (int mt = 0; mt < 2; ++mt)
      #pragma unroll
      for (int nt = 0; nt < 2; ++nt)
        acc[mt][nt] = __builtin_amdgcn_mfma_f32_16x16x32_bf16(af[mt], bfv[nt], acc[mt][nt], 0, 0, 0);
    __syncthreads();
  }
  #pragma unroll
  for (int mt = 0; mt < 2; ++mt)
  #pragma unroll
  for (int nt = 0; nt < 2; ++nt)
  #pragma unroll
  for (int j = 0; j < 4; ++j) {
    int row = m_base + wr * 32 + mt * 16 + lg * 4 + j;
    int col = n_base + wc * 32 + nt * 16 + lr;
    T[((size_t)row * 16 + h) * 2048 + col] = f2bf(acc[mt][nt][j]);
  }
}

// scores[b,h,s] = (t_b @ hist_b^T)/sqrt(HD)  -> softmax over s -> ATT f32 [b][h][s]
__global__ __launch_bounds__(256) void attn_scores(
    const unsigned short* __restrict__ T, const float* __restrict__ hist, float* __restrict__ ATT)
{
  const int t = threadIdx.x;
  const int wid = t >> 6, lane = t & 63, lr = lane & 15, lg = lane >> 4;
  const int b = blockIdx.x;
  __shared__ unsigned short lds_t[16 * 72];
  __shared__ unsigned short lds_h[64 * 72];
  __shared__ float sc[16 * 68];
  floatx4 acc = {};
  for (int kt = 0; kt < 32; ++kt) {
    { int row = t >> 4, c4 = t & 15;
      int k = kt * 64 + c4 * 4;
      ushort4 v = *(const ushort4*)(T + ((size_t)b * 16 + row) * 2048 + k);
      *(ushort4*)&lds_t[row * 72 + c4 * 4] = v; }
    #pragma unroll
    for (int rep = 0; rep < 4; ++rep) {
      int idx = t + rep * 256;
      int srow = idx >> 4, c4 = idx & 15;
      int k = kt * 64 + c4 * 4;
      float4 hv = *(const float4*)(hist + ((size_t)b * 64 + srow) * 2048 + k);
      ushort4 uv; uv.x = f2bf(hv.x); uv.y = f2bf(hv.y); uv.z = f2bf(hv.z); uv.w = f2bf(hv.w);
      *(ushort4*)&lds_h[srow * 72 + c4 * 4] = uv;
    }
    __syncthreads();
    #pragma unroll
    for (int ks = 0; ks < 2; ++ks) {
      shortx8 af = *(shortx8*)&lds_t[lr * 72 + ks * 32 + lg * 8];
      shortx8 bv = *(shortx8*)&lds_h[(wid * 16 + lr) * 72 + ks * 32 + lg * 8];
      acc = __builtin_amdgcn_mfma_f32_16x16x32_bf16(af, bv, acc, 0, 0, 0);
    }
    __syncthreads();
  }
  #pragma unroll
  for (int j = 0; j < 4; ++j)
    sc[(lg * 4 + j) * 68 + wid * 16 + lr] = acc[j] * 0.088388347648318447f;
  __syncthreads();
  if (t < 64) {
    int h = t >> 2, qd = t & 3;
    float vv[16];
    float m = -1e30f;
    #pragma unroll
    for (int z = 0; z < 16; ++z) { vv[z] = sc[h * 68 + qd * 16 + z]; m = fmaxf(m, vv[z]); }
    m = fmaxf(m, __shfl_xor(m, 1)); m = fmaxf(m, __shfl_xor(m, 2));
    float sum = 0.f;
    #pragma unroll
    for (int z = 0; z < 16; ++z) { vv[z] = expf(vv[z] - m); sum += vv[z]; }
    sum += __shfl_xor(sum, 1); sum += __shfl_xor(sum, 2);
    float inv = 1.f / sum;
    #pragma unroll
    for (int z = 0; z < 16; ++z)
      ATT[(size_t)b * 1024 + h * 64 + qd * 16 + z] = vv[z] * inv;
  }
}

// w[b,h,i] = sum_s attn[b,h,s]*hist[b,s,i]  (VALU, bf16 out into T buffer)
__global__ __launch_bounds__(256) void attn_w(
    const float* __restrict__ ATT, const float* __restrict__ hist, unsigned short* __restrict__ Wb)
{
  const int t = threadIdx.x;
  const int b = blockIdx.y;
  const int i0 = (blockIdx.x * 256 + t) * 4;
  __shared__ float lat[64 * 16];   // [s][h]
  #pragma unroll
  for (int rep = 0; rep < 4; ++rep) {
    int idx = t + rep * 256;
    int s = idx >> 4, h = idx & 15;
    lat[idx] = ATT[(size_t)b * 1024 + h * 64 + s];
  }
  __syncthreads();
  floatx4 acc[16] = {};
  for (int s = 0; s < 64; ++s) {
    float4 h4 = *(const float4*)(hist + ((size_t)b * 64 + s) * 2048 + i0);
    floatx4 hv = { h4.x, h4.y, h4.z, h4.w };
    #pragma unroll
    for (int g = 0; g < 4; ++g) {
      floatx4 a4 = *(floatx4*)&lat[s * 16 + g * 4];
      acc[g * 4 + 0] += a4.x * hv;
      acc[g * 4 + 1] += a4.y * hv;
      acc[g * 4 + 2] += a4.z * hv;
      acc[g * 4 + 3] += a4.w * hv;
    }
  }
  #pragma unroll
  for (int h = 0; h < 16; ++h) {
    ushort4 o;
    o.x = f2bf(acc[h][0]); o.y = f2bf(acc[h][1]); o.z = f2bf(acc[h][2]); o.w = f2bf(acc[h][3]);
    *(ushort4*)(Wb + ((size_t)b * 16 + h) * 2048 + i0) = o;
  }
}

// ctx[b, h*HD+n] = w[b,h,:] @ Wv[:, h*HD+n] + bv  (per-head GEMM, A already bf16)
__global__ __launch_bounds__(256) void gemm_ctx(
    const unsigned short* __restrict__ Wb, const float* __restrict__ Wv,
    const float* __restrict__ bv, float* __restrict__ CTX)
{
  const int t = threadIdx.x;
  const int wid = t >> 6, lane = t & 63, lr = lane & 15, lg = lane >> 4;
  const int wr = wid >> 1, wc = wid & 1;
  const int h = blockIdx.z;
  const int m_base = blockIdx.x * 64;
  __shared__ unsigned short lds_a[64 * 40];
  __shared__ unsigned short lds_b[128 * 40];
  floatx4 acc[2][4] = {};
  for (int kt = 0; kt < 64; ++kt) {
    { int arow = t >> 2, c8 = t & 3;
      int gk = kt * 32 + c8 * 8;
      uint4 v = *(const uint4*)(Wb + ((size_t)(m_base + arow) * 16 + h) * 2048 + gk);
      *(uint4*)&lds_a[arow * 40 + c8 * 8] = v; }
    { int tcol = t & 31, trow = t >> 5;
      #pragma unroll
      for (int rep = 0; rep < 2; ++rep) {
        int gk = kt * 32 + trow * 2 + rep * 16;
        float4 b0v = *(const float4*)(Wv + (size_t)gk * H_ + h * HD_ + tcol * 4);
        float4 b1v = *(const float4*)(Wv + (size_t)(gk + 1) * H_ + h * HD_ + tcol * 4);
        const float* p0 = &b0v.x; const float* p1 = &b1v.x;
        #pragma unroll
        for (int j = 0; j < 4; ++j) {
          ushort2 pr; pr.x = f2bf(p0[j]); pr.y = f2bf(p1[j]);
          *(ushort2*)&lds_b[(tcol * 4 + j) * 40 + trow * 2 + rep * 16] = pr;
        }
      } }
    __syncthreads();
    shortx8 af[2], bfv[4];
    #pragma unroll
    for (int mt = 0; mt < 2; ++mt)
      af[mt] = *(shortx8*)&lds_a[(wr * 32 + mt * 16 + lr) * 40 + lg * 8];
    #pragma unroll
    for (int nt = 0; nt < 4; ++nt)
      bfv[nt] = *(shortx8*)&lds_b[(wc * 64 + nt * 16 + lr) * 40 + lg * 8];
    #pragma unroll
    for (int mt = 0; mt < 2; ++mt)
      #pragma unroll
      for (int nt = 0; nt < 4; ++nt)
        acc[mt][nt] = __builtin_amdgcn_mfma_f32_16x16x32_bf16(af[mt], bfv[nt], acc[mt][nt], 0, 0, 0);
    __syncthreads();
  }
  #pragma unroll
  for (int mt = 0; mt < 2; ++mt)
  #pragma unroll
  for (int nt = 0; nt < 4; ++nt)
  #pragma unroll
  for (int j = 0; j < 4; ++j) {
    int row = m_base + wr * 32 + mt * 16 + lg * 4 + j;
    int cl = wc * 64 + nt * 16 + lr;
    int gcol = h * HD_ + cl;
    CTX[(size_t)row * H_ + gcol] = acc[mt][nt][j] + bv[gcol];
  }
}

__global__ __launch_bounds__(256) void lnorm(
    const float* __restrict__ X, const float* __restrict__ gma,
    const float* __restrict__ bta, float* __restrict__ out)
{
  const int row = blockIdx.x, t = threadIdx.x;
  float4 a = *(const float4*)(X + (size_t)row * 2048 + t * 4);
  float4 c = *(const float4*)(X + (size_t)row * 2048 + 1024 + t * 4);
  float sum = a.x + a.y + a.z + a.w + c.x + c.y + c.z + c.w;
  float sq = a.x*a.x + a.y*a.y + a.z*a.z + a.w*a.w + c.x*c.x + c.y*c.y + c.z*c.z + c.w*c.w;
  #pragma unroll
  for (int off = 1; off < 64; off <<= 1) {
    sum += __shfl_xor(sum, off);
    sq  += __shfl_xor(sq, off);
  }
  __shared__ float red[8];
  int wid = t >> 6, lane = t & 63;
  if (lane == 0) { red[wid] = sum; red[wid + 4] = sq; }
  __syncthreads();
  sum = red[0] + red[1] + red[2] + red[3];
  sq  = red[4] + red[5] + red[6] + red[7];
  float mu = sum * (1.f / 2048.f);
  float var = sq * (1.f / 2048.f) - mu * mu;
  float rs = rsqrtf(var + 1e-5f);
  const float* pa = &a.x; const float* pc = &c.x;
  #pragma unroll
  for (int j = 0; j < 4; ++j) {
    int col = t * 4 + j;
    out[(size_t)row * 2048 + col] = (pa[j] - mu) * rs * gma[col] + bta[col];
  }
  #pragma unroll
  for (int j = 0; j < 4; ++j) {
    int col = 1024 + t * 4 + j;
    out[(size_t)row * 2048 + col] = (pc[j] - mu) * rs * gma[col] + bta[col];
  }
}

extern "C" void kernel_launch(void* const* d_in, const int* in_sizes, int n_in,
                              void* d_out, int out_size, void* d_ws, size_t ws_size,
                              hipStream_t stream) {
  (void)in_sizes; (void)n_in; (void)out_size; (void)ws_size;
  // setup_inputs order: 0=x 1=high_state 2=high_states_history 3=hidden
  // 4=W_in 5=b_in 6=ts_emb 7=Wq 8=bq 9=Wk 10=bk 11=Wv 12=bv 13=Wo 14=bo
  // 15=Wu 16=Wr 17=Ws 18=Wc 19=bu 20=br 21=bs 22=bc 23=ln_g 24=ln_b 25=timestep
  const float* x      = (const float*)d_in[0];
  const float* hist   = (const float*)d_in[2];
  const float* hidden = (const float*)d_in[3];
  const float* W_in   = (const float*)d_in[4];
  const float* b_in   = (const float*)d_in[5];
  const float* ts_emb = (const float*)d_in[6];
  const float* Wq     = (const float*)d_in[7];
  const float* bq     = (const float*)d_in[8];
  const float* Wk     = (const float*)d_in[9];
  const float* Wv     = (const float*)d_in[11];
  const float* bv     = (const float*)d_in[12];
  const float* Wo     = (const float*)d_in[13];
  const float* bo     = (const float*)d_in[14];
  const float* Wu     = (const float*)d_in[15];
  const float* Wr     = (const float*)d_in[16];
  const float* Wsg    = (const float*)d_in[17];
  const float* Wc     = (const float*)d_in[18];
  const float* bu     = (const float*)d_in[19];
  const float* br     = (const float*)d_in[20];
  const float* bs     = (const float*)d_in[21];
  const float* bc     = (const float*)d_in[22];
  const float* ln_g   = (const float*)d_in[23];
  const float* ln_b   = (const float*)d_in[24];
  const int*   tsp    = (const int*)d_in[25];
  float* out = (float*)d_out;

  char* ws = (char*)d_ws;
  float* XIN = out;                                // [B,H] scratch in d_out[0:B*H]; lnorm overwrites last
  float* X2  = (float*)ws;                         // [B,H]
  float* Qb  = X2 + (size_t)B_ * H_;               // [B,H]  (later reused as CTX)
  float* Ub  = Qb + (size_t)B_ * H_;               // [B,H]
  float* Rb  = Ub + (size_t)B_ * H_;               // [B,H]
  float* Sb  = Rb + (size_t)B_ * H_;               // [B,H]
  float* ATT = Sb + (size_t)B_ * H_;               // [B,NH,S]
  unsigned short* Tb = (unsigned short*)(ATT + (size_t)B_ * NH_ * S_);  // bf16 [B,NH,HI] (later reused as w)

  dim3 blk(256);

  // 1) xin = x@W_in + b_in + ts_emb[t]
  gemm_std<EPI_TS, false, false, false><<<dim3(16, 32), blk, 0, stream>>>(
      1024, 2048, 2048, x, nullptr, nullptr, nullptr, W_in, nullptr, nullptr,
      b_in, nullptr, nullptr, ts_emb, tsp, nullptr, nullptr, nullptr, nullptr,
      XIN, nullptr, nullptr);
  // 2) q = xin@Wq + bq
  gemm_std<EPI_BIAS, false, false, false><<<dim3(16, 32), blk, 0, stream>>>(
      1024, 2048, 2048, XIN, nullptr, nullptr, nullptr, Wq, nullptr, nullptr,
      bq, nullptr, nullptr, nullptr, nullptr, nullptr, nullptr, nullptr, nullptr,
      Qb, nullptr, nullptr);
  // 3) T[b,h,:] = Wk_h^T q_bh
  gemm_t<<<dim3(16, 32, 16), blk, 0, stream>>>(Qb, Wk, Tb);
  // 4) scores + softmax
  attn_scores<<<dim3(1024), blk, 0, stream>>>(Tb, hist, ATT);
  // 5) w = attn @ hist  (overwrites Tb)
  attn_w<<<dim3(2, 1024), blk, 0, stream>>>(ATT, hist, Tb);
  // 6) ctx = w @ Wv + bv  (into Qb)
  gemm_ctx<<<dim3(16, 1, 16), blk, 0, stream>>>(Tb, Wv, bv, Qb);
  // 7) x2 = xin + ctx@Wo + bo
  gemm_std<EPI_RES, false, false, false><<<dim3(16, 32), blk, 0, stream>>>(
      1024, 2048, 2048, Qb, nullptr, nullptr, nullptr, Wo, nullptr, nullptr,
      bo, nullptr, nullptr, nullptr, nullptr, XIN, nullptr, nullptr, nullptr,
      X2, nullptr, nullptr);

  // 8) recurrent layers
  const float* xin_l = X2;
  for (int i = 0; i < L_; ++i) {
    const float* h_i = hidden + (size_t)i * B_ * H_;
    float* nh = out + (size_t)B_ * H_ + (size_t)i * B_ * H_;
    gemm_std<EPI_SIG, true, false, true><<<dim3(16, 32, 3), blk, 0, stream>>>(
        1024, 2048, 4096, nullptr, xin_l, h_i, nullptr,
        Wu + (size_t)i * H2_ * H_, Wr + (size_t)i * H2_ * H_, Wsg + (size_t)i * H2_ * H_,
        bu + (size_t)i * H_, br + (size_t)i * H_, bs + (size_t)i * H_,
        nullptr, nullptr, nullptr, nullptr, nullptr, nullptr,
        Ub, Rb, Sb);
    gemm_std<EPI_GRU, true, true, false><<<dim3(16, 32), blk, 0, stream>>>(
        1024, 2048, 4096, nullptr, xin_l, h_i, Rb,
        Wc + (size_t)i * H2_ * H_, nullptr, nullptr,
        bc + (size_t)i * H_, nullptr, nullptr,
        nullptr, nullptr, nullptr, Ub, Sb, h_i,
        nh, nullptr, nullptr);
    xin_l = nh;
  }

  // 9) layernorm of final hidden -> out[0:B*H]
  lnorm<<<dim3(1024), blk, 0, stream>>>(
      out + (size_t)B_ * H_ + (size_t)3 * B_ * H_, ln_g, ln_b, out);
}

// Round 3
// 1480.486 us; speedup vs baseline: 1.9662x; 1.9662x over previous
//
#include <hip/hip_runtime.h>
#include <hip/hip_bf16.h>
#include <math.h>

#define B_  1024
#define S_  64
#define H_  2048
#define L_  4
#define NH_ 16
#define HD_ 128

typedef __attribute__((ext_vector_type(4))) float floatx4;
typedef __attribute__((ext_vector_type(8))) short shortx8;

__device__ __forceinline__ unsigned short f2bf(float f) {
  union { float f; unsigned int u; } v; v.f = f;
  unsigned int u = v.u;
  return (unsigned short)((u + 0x7fffu + ((u >> 16) & 1u)) >> 16);
}

// async global->LDS, 16B per lane; LDS dest = wave-uniform base + lane*16
__device__ __forceinline__ void gload16(const void* g, void* l) {
  __builtin_amdgcn_global_load_lds(
      (const __attribute__((address_space(1))) void*)g,
      (__attribute__((address_space(3))) void*)l, 16, 0, 0);
}

// f32 -> bf16 elementwise (8 per thread)
__global__ __launch_bounds__(256) void cvt_bf(
    const float* __restrict__ in, unsigned short* __restrict__ out, int n8)
{
  int i = blockIdx.x * 256 + threadIdx.x;
  if (i >= n8) return;
  const float4* p = (const float4*)in;
  float4 a = p[i * 2], b = p[i * 2 + 1];
  unsigned short o[8] = { f2bf(a.x), f2bf(a.y), f2bf(a.z), f2bf(a.w),
                          f2bf(b.x), f2bf(b.y), f2bf(b.z), f2bf(b.w) };
  ((uint4*)out)[i] = *(uint4*)o;
}

// transpose-convert: dst[z] bf16 [2048 n][K k] from src_z f32 [K][2048]
__global__ __launch_bounds__(256) void tconv4(
    const float* __restrict__ s0, const float* __restrict__ s1,
    const float* __restrict__ s2, const float* __restrict__ s3,
    unsigned short* __restrict__ dst, int K)
{
  const float* src = (blockIdx.z == 0) ? s0 : (blockIdx.z == 1) ? s1
                   : (blockIdx.z == 2) ? s2 : s3;
  unsigned short* out = dst + (size_t)blockIdx.z * 2048 * K;
  __shared__ float tile[64][65];
  int k0 = blockIdx.x * 64, n0 = blockIdx.y * 64;
  int t = threadIdx.x;
  int tr = t >> 4, tc = (t & 15) * 4;
  #pragma unroll
  for (int rep = 0; rep < 4; ++rep) {
    int kk = tr + rep * 16;
    float4 v = *(const float4*)(src + (size_t)(k0 + kk) * 2048 + n0 + tc);
    tile[kk][tc] = v.x; tile[kk][tc + 1] = v.y;
    tile[kk][tc + 2] = v.z; tile[kk][tc + 3] = v.w;
  }
  __syncthreads();
  int nr = t >> 2, kc = (t & 3) * 16;
  unsigned short o[16];
  #pragma unroll
  for (int j = 0; j < 16; ++j) o[j] = f2bf(tile[kc + j][nr]);
  *(uint4*)(out + (size_t)(n0 + nr) * K + k0 + kc)     = *(uint4*)&o[0];
  *(uint4*)(out + (size_t)(n0 + nr) * K + k0 + kc + 8) = *(uint4*)&o[8];
}

enum { EPI_XIN = 0, EPI_QB = 1, EPI_X2 = 2, EPI_GATE = 3, EPI_GRU = 4 };

// C[M,2048] = epi(A[M,K]bf16 @ BT[2048,K]bf16^T). Tile BM x 128, BK=32.
// MF=4 -> BM=128 (acc 4x4/wave); MF=2 -> BM=64 (acc 2x4/wave). 4 waves.
// LDS linear + XOR chunk swizzle (chunk ^= (row>>1)&3), source inverse-swizzled.
template<int EPI, bool CONCAT, int MF>
__global__ __launch_bounds__(256) void gemm128(
    int K,
    const unsigned short* __restrict__ A0, const unsigned short* __restrict__ A1,
    const unsigned short* __restrict__ BT,
    const float* __restrict__ b0, const float* __restrict__ b1, const float* __restrict__ b2,
    const float* __restrict__ tse, const int* __restrict__ tsp,
    const float* __restrict__ res,
    float* __restrict__ Up, float* __restrict__ Sp,
    const float* __restrict__ Hf,
    float* __restrict__ Cf, unsigned short* __restrict__ Cb)
{
  constexpr int BM = MF * 32;
  const int t = threadIdx.x, wid = t >> 6, lane = t & 63, lr = lane & 15, lg = lane >> 4;
  const int wr = wid >> 1, wc = wid & 1;
  const int m_base = blockIdx.x * BM, n_base = blockIdx.y * 128;
  const int z = blockIdx.z;
  const unsigned short* BTz = BT + (size_t)z * 2048 * K;
  __shared__ unsigned short lds_a[BM * 32];
  __shared__ unsigned short lds_b[128 * 32];
  floatx4 acc[MF][4] = {};
  const int nkt = K >> 5;
  for (int kt = 0; kt < nkt; ++kt) {
    #pragma unroll
    for (int is = 0; is < BM / 64; ++is) {
      int idx = is * 256 + t;
      int row = idx >> 2, kc = idx & 3;
      int kcs = kc ^ ((row >> 1) & 3);
      int gk = kt * 32 + kcs * 8;
      const unsigned short* ga;
      if (!CONCAT) ga = A0 + (size_t)(m_base + row) * K + gk;
      else ga = (gk < 2048) ? A0 + (size_t)(m_base + row) * 2048 + gk
                            : A1 + (size_t)(m_base + row) * 2048 + (gk - 2048);
      gload16(ga, &lds_a[(is * 256 + wid * 64) * 8]);
    }
    #pragma unroll
    for (int is = 0; is < 2; ++is) {
      int idx = is * 256 + t;
      int row = idx >> 2, kc = idx & 3;
      int kcs = kc ^ ((row >> 1) & 3);
      int gk = kt * 32 + kcs * 8;
      gload16(BTz + (size_t)(n_base + row) * K + gk, &lds_b[(is * 256 + wid * 64) * 8]);
    }
    __syncthreads();
    const int sl = lg ^ ((lr >> 1) & 3);
    shortx8 af[MF], bfv[4];
    #pragma unroll
    for (int mt = 0; mt < MF; ++mt)
      af[mt] = *(shortx8*)&lds_a[(wr * (MF * 16) + mt * 16 + lr) * 32 + sl * 8];
    #pragma unroll
    for (int nt = 0; nt < 4; ++nt)
      bfv[nt] = *(shortx8*)&lds_b[(wc * 64 + nt * 16 + lr) * 32 + sl * 8];
    #pragma unroll
    for (int mt = 0; mt < MF; ++mt)
      #pragma unroll
      for (int nt = 0; nt < 4; ++nt)
        acc[mt][nt] = __builtin_amdgcn_mfma_f32_16x16x32_bf16(af[mt], bfv[nt], acc[mt][nt], 0, 0, 0);
    __syncthreads();
  }
  const float* bias = b0;
  if (EPI == EPI_GATE) bias = (z == 0) ? b0 : (z == 1) ? b1 : b2;
  int ts = 0;
  if (EPI == EPI_XIN) ts = tsp[0];
  #pragma unroll
  for (int mt = 0; mt < MF; ++mt)
  #pragma unroll
  for (int nt = 0; nt < 4; ++nt)
  #pragma unroll
  for (int j = 0; j < 4; ++j) {
    int row = m_base + wr * (MF * 16) + mt * 16 + lg * 4 + j;
    int col = n_base + wc * 64 + nt * 16 + lr;
    size_t idx = (size_t)row * 2048 + col;
    float v = acc[mt][nt][j] + bias[col];
    if (EPI == EPI_XIN) {
      v += tse[(size_t)ts * 2048 + col];
      Cf[idx] = v; Cb[idx] = f2bf(v);
    } else if (EPI == EPI_QB) {
      Cb[idx] = f2bf(v);
    } else if (EPI == EPI_X2) {
      v += res[idx]; Cb[idx] = f2bf(v);
    } else if (EPI == EPI_GATE) {
      v = 1.f / (1.f + expf(-v));
      if (z == 0) Up[idx] = v;
      else if (z == 1) Cb[idx] = f2bf(v * Hf[idx]);
      else Sp[idx] = v;
    } else {
      float g = 0.5f * v * (1.f + erff(v * 0.70710678118654752f));
      float u = Up[idx], s = Sp[idx], hh = Hf[idx];
      float nh = (1.f - u) * hh + u * (s * g + (1.f - s) * hh);
      Cf[idx] = nh; Cb[idx] = f2bf(nh);
    }
  }
}

// T[b,h,i] = sum_d q[b,h*128+d] * Wk[i,h*128+d]; q,Wk bf16; 64x64 tile, K=128
__global__ __launch_bounds__(256) void gemm_t(
    const unsigned short* __restrict__ Q, const unsigned short* __restrict__ Wk,
    unsigned short* __restrict__ T)
{
  const int t = threadIdx.x, wid = t >> 6, lane = t & 63, lr = lane & 15, lg = lane >> 4;
  const int wr = wid >> 1, wc = wid & 1;
  const int h = blockIdx.z, m_base = blockIdx.x * 64, n_base = blockIdx.y * 64;
  __shared__ unsigned short lds_a[64 * 32], lds_b[64 * 32];
  floatx4 acc[2][2] = {};
  const int row = t >> 2, kc = t & 3;
  const int kcs = kc ^ ((row >> 1) & 3);
  for (int kt = 0; kt < 4; ++kt) {
    int gk = kt * 32 + kcs * 8;
    gload16(Q  + (size_t)(m_base + row) * 2048 + h * 128 + gk, &lds_a[wid * 512]);
    gload16(Wk + (size_t)(n_base + row) * 2048 + h * 128 + gk, &lds_b[wid * 512]);
    __syncthreads();
    const int sl = lg ^ ((lr >> 1) & 3);
    shortx8 af[2], bfv[2];
    #pragma unroll
    for (int mt = 0; mt < 2; ++mt)
      af[mt] = *(shortx8*)&lds_a[(wr * 32 + mt * 16 + lr) * 32 + sl * 8];
    #pragma unroll
    for (int nt = 0; nt < 2; ++nt)
      bfv[nt] = *(shortx8*)&lds_b[(wc * 32 + nt * 16 + lr) * 32 + sl * 8];
    #pragma unroll
    for (int mt = 0; mt < 2; ++mt)
      #pragma unroll
      for (int nt = 0; nt < 2; ++nt)
        acc[mt][nt] = __builtin_amdgcn_mfma_f32_16x16x32_bf16(af[mt], bfv[nt], acc[mt][nt], 0, 0, 0);
    __syncthreads();
  }
  #pragma unroll
  for (int mt = 0; mt < 2; ++mt)
  #pragma unroll
  for (int nt = 0; nt < 2; ++nt)
  #pragma unroll
  for (int j = 0; j < 4; ++j) {
    int row_o = m_base + wr * 32 + mt * 16 + lg * 4 + j;
    int col   = n_base + wc * 32 + nt * 16 + lr;
    T[((size_t)row_o * 16 + h) * 2048 + col] = f2bf(acc[mt][nt][j]);
  }
}

// scores+softmax: unchanged from R2 (reads bf16 T + f32 hist)
__global__ __launch_bounds__(256) void attn_scores(
    const unsigned short* __restrict__ T, const float* __restrict__ hist, float* __restrict__ ATT)
{
  const int t = threadIdx.x;
  const int wid = t >> 6, lane = t & 63, lr = lane & 15, lg = lane >> 4;
  const int b = blockIdx.x;
  __shared__ unsigned short lds_t[16 * 72];
  __shared__ unsigned short lds_h[64 * 72];
  __shared__ float sc[16 * 68];
  floatx4 acc = {};
  for (int kt = 0; kt < 32; ++kt) {
    { int row = t >> 4, c4 = t & 15;
      int k = kt * 64 + c4 * 4;
      ushort4 v = *(const ushort4*)(T + ((size_t)b * 16 + row) * 2048 + k);
      *(ushort4*)&lds_t[row * 72 + c4 * 4] = v; }
    #pragma unroll
    for (int rep = 0; rep < 4; ++rep) {
      int idx = t + rep * 256;
      int srow = idx >> 4, c4 = idx & 15;
      int k = kt * 64 + c4 * 4;
      float4 hv = *(const float4*)(hist + ((size_t)b * 64 + srow) * 2048 + k);
      ushort4 uv; uv.x = f2bf(hv.x); uv.y = f2bf(hv.y); uv.z = f2bf(hv.z); uv.w = f2bf(hv.w);
      *(ushort4*)&lds_h[srow * 72 + c4 * 4] = uv;
    }
    __syncthreads();
    #pragma unroll
    for (int ks = 0; ks < 2; ++ks) {
      shortx8 af = *(shortx8*)&lds_t[lr * 72 + ks * 32 + lg * 8];
      shortx8 bv = *(shortx8*)&lds_h[(wid * 16 + lr) * 72 + ks * 32 + lg * 8];
      acc = __builtin_amdgcn_mfma_f32_16x16x32_bf16(af, bv, acc, 0, 0, 0);
    }
    __syncthreads();
  }
  #pragma unroll
  for (int j = 0; j < 4; ++j)
    sc[(lg * 4 + j) * 68 + wid * 16 + lr] = acc[j] * 0.088388347648318447f;
  __syncthreads();
  if (t < 64) {
    int h = t >> 2, qd = t & 3;
    float vv[16];
    float m = -1e30f;
    #pragma unroll
    for (int zz = 0; zz < 16; ++zz) { vv[zz] = sc[h * 68 + qd * 16 + zz]; m = fmaxf(m, vv[zz]); }
    m = fmaxf(m, __shfl_xor(m, 1)); m = fmaxf(m, __shfl_xor(m, 2));
    float sum = 0.f;
    #pragma unroll
    for (int zz = 0; zz < 16; ++zz) { vv[zz] = expf(vv[zz] - m); sum += vv[zz]; }
    sum += __shfl_xor(sum, 1); sum += __shfl_xor(sum, 2);
    float inv = 1.f / sum;
    #pragma unroll
    for (int zz = 0; zz < 16; ++zz)
      ATT[(size_t)b * 1024 + h * 64 + qd * 16 + zz] = vv[zz] * inv;
  }
}

// w[b,h,i] = sum_s attn[b,h,s]*hist[b,s,i]  (bf16 out into T buffer)
__global__ __launch_bounds__(256) void attn_w(
    const float* __restrict__ ATT, const float* __restrict__ hist, unsigned short* __restrict__ Wb)
{
  const int t = threadIdx.x;
  const int b = blockIdx.y;
  const int i0 = (blockIdx.x * 256 + t) * 4;
  __shared__ float lat[64 * 16];
  #pragma unroll
  for (int rep = 0; rep < 4; ++rep) {
    int idx = t + rep * 256;
    int s = idx >> 4, h = idx & 15;
    lat[idx] = ATT[(size_t)b * 1024 + h * 64 + s];
  }
  __syncthreads();
  floatx4 acc[16] = {};
  for (int s = 0; s < 64; ++s) {
    float4 h4 = *(const float4*)(hist + ((size_t)b * 64 + s) * 2048 + i0);
    floatx4 hv = { h4.x, h4.y, h4.z, h4.w };
    #pragma unroll
    for (int g = 0; g < 4; ++g) {
      floatx4 a4 = *(floatx4*)&lat[s * 16 + g * 4];
      acc[g * 4 + 0] += a4.x * hv;
      acc[g * 4 + 1] += a4.y * hv;
      acc[g * 4 + 2] += a4.z * hv;
      acc[g * 4 + 3] += a4.w * hv;
    }
  }
  #pragma unroll
  for (int h = 0; h < 16; ++h) {
    ushort4 o;
    o.x = f2bf(acc[h][0]); o.y = f2bf(acc[h][1]); o.z = f2bf(acc[h][2]); o.w = f2bf(acc[h][3]);
    *(ushort4*)(Wb + ((size_t)b * 16 + h) * 2048 + i0) = o;
  }
}

// ctx bf16[b, h*128+n] = w[b,h,:] @ WvT[h*128+n,:] + bv
__global__ __launch_bounds__(256) void gemm_ctx(
    const unsigned short* __restrict__ Wb, const unsigned short* __restrict__ WvT,
    const float* __restrict__ bv, unsigned short* __restrict__ ctx)
{
  const int t = threadIdx.x, wid = t >> 6, lane = t & 63, lr = lane & 15, lg = lane >> 4;
  const int wr = wid >> 1, wc = wid & 1;
  const int h = blockIdx.z, m_base = blockIdx.x * 64;
  __shared__ unsigned short lds_a[64 * 32], lds_b[128 * 32];
  floatx4 acc[2][4] = {};
  const int row = t >> 2, kc = t & 3;
  const int kcs = kc ^ ((row >> 1) & 3);
  for (int kt = 0; kt < 64; ++kt) {
    int gk = kt * 32 + kcs * 8;
    gload16(Wb  + ((size_t)(m_base + row) * 16 + h) * 2048 + gk, &lds_a[wid * 512]);
    gload16(WvT + (size_t)(h * 128 + row) * 2048 + gk,           &lds_b[wid * 512]);
    gload16(WvT + (size_t)(h * 128 + 64 + row) * 2048 + gk,      &lds_b[2048 + wid * 512]);
    __syncthreads();
    const int sl = lg ^ ((lr >> 1) & 3);
    shortx8 af[2], bfv[4];
    #pragma unroll
    for (int mt = 0; mt < 2; ++mt)
      af[mt] = *(shortx8*)&lds_a[(wr * 32 + mt * 16 + lr) * 32 + sl * 8];
    #pragma unroll
    for (int nt = 0; nt < 4; ++nt)
      bfv[nt] = *(shortx8*)&lds_b[(wc * 64 + nt * 16 + lr) * 32 + sl * 8];
    #pragma unroll
    for (int mt = 0; mt < 2; ++mt)
      #pragma unroll
      for (int nt = 0; nt < 4; ++nt)
        acc[mt][nt] = __builtin_amdgcn_mfma_f32_16x16x32_bf16(af[mt], bfv[nt], acc[mt][nt], 0, 0, 0);
    __syncthreads();
  }
  #pragma unroll
  for (int mt = 0; mt < 2; ++mt)
  #pragma unroll
  for (int nt = 0; nt < 4; ++nt)
  #pragma unroll
  for (int j = 0; j < 4; ++j) {
    int row_o = m_base + wr * 32 + mt * 16 + lg * 4 + j;
    int cl = wc * 64 + nt * 16 + lr;
    int gcol = h * 128 + cl;
    ctx[(size_t)row_o * 2048 + gcol] = f2bf(acc[mt][nt][j] + bv[gcol]);
  }
}

__global__ __launch_bounds__(256) void lnorm(
    const float* __restrict__ X, const float* __restrict__ gma,
    const float* __restrict__ bta, float* __restrict__ out)
{
  const int row = blockIdx.x, t = threadIdx.x;
  float4 a = *(const float4*)(X + (size_t)row * 2048 + t * 4);
  float4 c = *(const float4*)(X + (size_t)row * 2048 + 1024 + t * 4);
  float sum = a.x + a.y + a.z + a.w + c.x + c.y + c.z + c.w;
  float sq = a.x*a.x + a.y*a.y + a.z*a.z + a.w*a.w + c.x*c.x + c.y*c.y + c.z*c.z + c.w*c.w;
  #pragma unroll
  for (int off = 1; off < 64; off <<= 1) {
    sum += __shfl_xor(sum, off);
    sq  += __shfl_xor(sq, off);
  }
  __shared__ float red[8];
  int wid = t >> 6, lane = t & 63;
  if (lane == 0) { red[wid] = sum; red[wid + 4] = sq; }
  __syncthreads();
  sum = red[0] + red[1] + red[2] + red[3];
  sq  = red[4] + red[5] + red[6] + red[7];
  float mu = sum * (1.f / 2048.f);
  float var = sq * (1.f / 2048.f) - mu * mu;
  float rs = rsqrtf(var + 1e-5f);
  const float* pa = &a.x; const float* pc = &c.x;
  #pragma unroll
  for (int j = 0; j < 4; ++j) {
    int col = t * 4 + j;
    out[(size_t)row * 2048 + col] = (pa[j] - mu) * rs * gma[col] + bta[col];
  }
  #pragma unroll
  for (int j = 0; j < 4; ++j) {
    int col = 1024 + t * 4 + j;
    out[(size_t)row * 2048 + col] = (pc[j] - mu) * rs * gma[col] + bta[col];
  }
}

extern "C" void kernel_launch(void* const* d_in, const int* in_sizes, int n_in,
                              void* d_out, int out_size, void* d_ws, size_t ws_size,
                              hipStream_t stream) {
  (void)in_sizes; (void)n_in; (void)out_size; (void)ws_size;
  const float* x      = (const float*)d_in[0];
  const float* hist   = (const float*)d_in[2];
  const float* hidden = (const float*)d_in[3];
  const float* W_in   = (const float*)d_in[4];
  const float* b_in   = (const float*)d_in[5];
  const float* ts_emb = (const float*)d_in[6];
  const float* Wq     = (const float*)d_in[7];
  const float* bq     = (const float*)d_in[8];
  const float* Wk     = (const float*)d_in[9];
  const float* Wv     = (const float*)d_in[11];
  const float* bv     = (const float*)d_in[12];
  const float* Wo     = (const float*)d_in[13];
  const float* bo     = (const float*)d_in[14];
  const float* Wu     = (const float*)d_in[15];
  const float* Wr     = (const float*)d_in[16];
  const float* Wsg    = (const float*)d_in[17];
  const float* Wc     = (const float*)d_in[18];
  const float* bu     = (const float*)d_in[19];
  const float* br     = (const float*)d_in[20];
  const float* bs     = (const float*)d_in[21];
  const float* bc     = (const float*)d_in[22];
  const float* ln_g   = (const float*)d_in[23];
  const float* ln_b   = (const float*)d_in[24];
  const int*   tsp    = (const int*)d_in[25];
  float* out = (float*)d_out;

  const size_t BH = (size_t)B_ * H_;            // 2097152
  const size_t WSLAB = (size_t)H_ * 4096;       // 8388608 (gate slab elems)
  char* w = (char*)d_ws;
  auto take = [&](size_t bytes) { char* p = w; w += bytes; return p; };

  unsigned short* TW   = (unsigned short*)take((size_t)4 * WSLAB * 2);  // 64MiB; aliased Tb
  unsigned short* Tb   = TW;
  unsigned short* WT4  = (unsigned short*)take((size_t)4 * H_ * H_ * 2); // WinT,WqT,WvT,WoT
  unsigned short* WinT = WT4;
  unsigned short* WqT  = WT4 + (size_t)H_ * H_;
  unsigned short* WvT  = WT4 + (size_t)2 * H_ * H_;
  unsigned short* WoT  = WT4 + (size_t)3 * H_ * H_;
  unsigned short* Wkb  = (unsigned short*)take((size_t)H_ * H_ * 2);
  unsigned short* x_bf   = (unsigned short*)take(BH * 2);
  unsigned short* h_bf   = (unsigned short*)take((size_t)L_ * BH * 2);
  unsigned short* xin_bf = (unsigned short*)take(BH * 2);
  unsigned short* q_bf   = (unsigned short*)take(BH * 2);
  unsigned short* ctx_bf = (unsigned short*)take(BH * 2);
  unsigned short* x2_bf  = (unsigned short*)take(BH * 2);
  unsigned short* rh_bf  = (unsigned short*)take(BH * 2);
  unsigned short* xa     = (unsigned short*)take(BH * 2);
  unsigned short* xb     = (unsigned short*)take(BH * 2);
  float* U   = (float*)take(BH * 4);
  float* Sg  = (float*)take(BH * 4);
  float* ATT = (float*)take((size_t)B_ * NH_ * S_ * 4);
  float* XIN = out;   // f32 scratch in d_out[0:B*H]; overwritten by lnorm at end

  dim3 blk(256);

  // input conversions
  cvt_bf<<<dim3(1024), blk, 0, stream>>>(x, x_bf, (int)(BH / 8));
  cvt_bf<<<dim3(4096), blk, 0, stream>>>(hidden, h_bf, (int)(L_ * BH / 8));
  cvt_bf<<<dim3(2048), blk, 0, stream>>>(Wk, Wkb, (int)((size_t)H_ * H_ / 8));
  // small weight transposes: W_in, Wq, Wv, Wo -> [2048][2048] bf16 B^T
  tconv4<<<dim3(32, 32, 4), blk, 0, stream>>>(W_in, Wq, Wv, Wo, WT4, 2048);

  // 1) xin = x@W_in + b_in + ts_emb[t]   (f32 XIN + bf16)
  gemm128<EPI_XIN, false, 2><<<dim3(16, 16, 1), blk, 0, stream>>>(
      2048, x_bf, nullptr, WinT, b_in, nullptr, nullptr, ts_emb, tsp,
      nullptr, nullptr, nullptr, nullptr, XIN, xin_bf);
  // 2) q = xin@Wq + bq  (bf16)
  gemm128<EPI_QB, false, 2><<<dim3(16, 16, 1), blk, 0, stream>>>(
      2048, xin_bf, nullptr, WqT, bq, nullptr, nullptr, nullptr, nullptr,
      nullptr, nullptr, nullptr, nullptr, nullptr, q_bf);
  // 3) T = per-head Wk^T q
  gemm_t<<<dim3(16, 32, 16), blk, 0, stream>>>(q_bf, Wkb, Tb);
  // 4) scores + softmax
  attn_scores<<<dim3(1024), blk, 0, stream>>>(Tb, hist, ATT);
  // 5) w = attn @ hist (overwrites Tb)
  attn_w<<<dim3(2, 1024), blk, 0, stream>>>(ATT, hist, Tb);
  // 6) ctx = w @ Wv + bv (bf16)
  gemm_ctx<<<dim3(16, 1, 16), blk, 0, stream>>>(Tb, WvT, bv, ctx_bf);
  // 7) x2 = xin + ctx@Wo + bo (bf16)
  gemm128<EPI_X2, false, 2><<<dim3(16, 16, 1), blk, 0, stream>>>(
      2048, ctx_bf, nullptr, WoT, bo, nullptr, nullptr, nullptr, nullptr,
      XIN, nullptr, nullptr, nullptr, nullptr, x2_bf);

  // 8) recurrent layers
  unsigned short* xcur = x2_bf;
  for (int i = 0; i < L_; ++i) {
    const float* h_i = hidden + (size_t)i * BH;
    float* nh_f = out + BH + (size_t)i * BH;
    unsigned short* nh_b = (i & 1) ? xb : xa;
    // gate weight transposes for this layer (TW aliases Tb; last Tb read was step 6)
    tconv4<<<dim3(64, 32, 4), blk, 0, stream>>>(
        Wu + (size_t)i * WSLAB, Wr + (size_t)i * WSLAB,
        Wsg + (size_t)i * WSLAB, Wc + (size_t)i * WSLAB, TW, 4096);
    // G1: u,r,s gates; r-gate writes bf16 r*h
    gemm128<EPI_GATE, true, 4><<<dim3(8, 16, 3), blk, 0, stream>>>(
        4096, xcur, h_bf + (size_t)i * BH, TW,
        bu + (size_t)i * H_, br + (size_t)i * H_, bs + (size_t)i * H_,
        nullptr, nullptr, nullptr, U, Sg, h_i, nullptr, rh_bf);
    // G2: cand + GRU combine
    gemm128<EPI_GRU, true, 2><<<dim3(16, 16, 1), blk, 0, stream>>>(
        4096, xcur, rh_bf, TW + (size_t)3 * WSLAB,
        bc + (size_t)i * H_, nullptr, nullptr, nullptr, nullptr,
        nullptr, U, Sg, h_i, nh_f, nh_b);
    xcur = nh_b;
  }

  // 9) layernorm of final hidden -> out[0:B*H]
  lnorm<<<dim3(1024), blk, 0, stream>>>(out + BH + (size_t)3 * BH, ln_g, ln_b, out);
}